// Round 8
// baseline (342.137 us; speedup 1.0000x reference)
//
#include <hip/hip_runtime.h>
#include <math.h>

#define D 4096
#define WPB 4      // waves per workgroup (256 threads); private 16 KiB LDS slice each
#define NBLK 512   // persistent: 2 WGs per CU (2 x 64 KiB LDS = 128 <= 160 KiB)

// In-register FWHT over the 6 bits of the register index (64 values/thread).
__device__ __forceinline__ void fwht64(float* v) {
#pragma unroll
    for (int h = 1; h < 64; h <<= 1) {
#pragma unroll
        for (int i = 0; i < 64; i += 2 * h) {
#pragma unroll
            for (int j = i; j < i + h; ++j) {
                const float a = v[j];
                const float b = v[j + h];
                v[j]     = a + b;
                v[j + h] = a - b;
            }
        }
    }
}

// Precompute g = g_mu + softplus(g_rho)*eps, pre-permuted into layout-B order:
// gq[l*64 + k] = g[e(k,l)], e = (l&3) | (k<<2) | ((l>>2)<<8)
__global__ void whvi_prep(const float* __restrict__ g_mu,
                          const float* __restrict__ g_rho,
                          const float* __restrict__ eps,
                          float* __restrict__ gq) {
    const int i = blockIdx.x * 64 + threadIdx.x;   // i = l*64 + k
    const int l = i >> 6, k = i & 63;
    const int e = (l & 3) | (k << 2) | ((l >> 2) << 8);
    const float r  = g_rho[e];
    const float sp = (r > 20.f) ? r : log1pf(expf(r));   // stable softplus
    gq[i] = g_mu[e] + sp * eps[e];
}

// PERSISTENT kernel, VGPR-budget 128 via __launch_bounds__(256, 2).
//
// RESIDENCY MODEL (fits all 6 measured rounds): VGPR budget = 256/waves_per_eu
// (r1 (64,4)->64; r5 (512,2)->128; flat-1024 default->64); HW residency
// follows the same pool-256 arithmetic: VGPR>128 => 1 wave/SIMD => ~3.4
// waves/CU measured in r0/r4/r7 REGARDLESS of dispatch structure (r7 was
// persistent, zero dispatch, still 3.4). VGPR<=128 => 2 waves/SIMD (r5: 6
// waves/CU even while spilling). THIS round's one change vs r7: (256,2).
//
// SPILL LEDGER: v[64] is the irreducible live set (~64 regs + temps ~110).
//   r5 spilled at budget-128 because xn[16] prefetch added 64 ALGORITHMIC regs.
//   NO cross-phase register arrays allowed. Spill canary: WRITE_SIZE must be
//   exactly 131072 KB (ideal out traffic); FETCH ~66 MB.
//
// Structure: 512 WGs x 4 waves, all resident (2 WGs/CU), each wave
// grid-strides over 4 rows with a PRIVATE 16 KiB LDS slice. No
// __syncthreads(): transposes are wave-local, ordered by `s_waitcnt
// lgkmcnt(0)` + "memory" clobber (proven correct r5/r7).
//
// Layout A: lane l, reg r holds element e = (r&3) | (l<<2) | ((r>>2)<<8)
// Layout B: lane l, reg k holds element e = (l&3) | (k<<2) | ((l>>2)<<8)
// regFWHT(A) -> transpose -> regFWHT(B) covers all 12 bits. LDS xor-swizzle
// sigma(e)=e^((e>>6)&0x1C): b128 writes minimal-phase, b32 reads <=2-way (free).
__global__ void __launch_bounds__(WPB * 64, 2) whvi_main(
    const float* __restrict__ x,  const float* __restrict__ s1,
    const float* __restrict__ s2, const float* __restrict__ gq,
    const float* __restrict__ g_mu, const float* __restrict__ g_rho,
    const float* __restrict__ eps, float* __restrict__ out, int rows) {
    __shared__ alignas(16) float lds_all[WPB * D];   // 64 KiB
    const int tid = threadIdx.x;
    const int w   = tid >> 6;                        // wave id in WG
    const int l   = tid & 63;                        // lane id
    float* lds = lds_all + (w << 12);                // private 16 KiB slice
    const int gw = blockIdx.x * WPB + w;             // global wave id
    const int nw = NBLK * WPB;                       // total waves (2048)
    const int xb = (l & 3) | ((l >> 2) << 8);        // layout-B read base
    const int mk = (l >> 2) & 7;                     // swizzle mask

#pragma clang loop unroll(disable)
    for (long long row = gw; row < rows; row += nw) {
        const float* xr = x + row * (long long)D;
        float v[64];

        // ---- load x*s2, layout A (coalesced dwordx4); consume immediately
        //      so live temps stay shallow under the 128-reg budget ----
#pragma unroll
        for (int q = 0; q < 16; ++q) {
            const int base = (l << 2) + (q << 8);
            const float4 xv = *reinterpret_cast<const float4*>(xr + base);
            const float4 sv = *reinterpret_cast<const float4*>(s2 + base);
            v[4 * q + 0] = xv.x * sv.x;
            v[4 * q + 1] = xv.y * sv.y;
            v[4 * q + 2] = xv.z * sv.z;
            v[4 * q + 3] = xv.w * sv.w;
        }

        fwht64(v);                   // FWHT-1a: e-bits {0,1,8,9,10,11}

        // ---- transpose 1: write layout A (b128, swizzled), read layout B (b32) ----
#pragma unroll
        for (int q = 0; q < 16; ++q) {
            const int addr = ((l ^ (q & 7)) << 2) + (q << 8);
            *reinterpret_cast<float4*>(&lds[addr]) =
                make_float4(v[4 * q], v[4 * q + 1], v[4 * q + 2], v[4 * q + 3]);
        }
        asm volatile("s_waitcnt lgkmcnt(0)" ::: "memory");   // writes visible (wave-local)
#pragma unroll
        for (int k = 0; k < 64; ++k)
            v[k] = lds[xb + ((k ^ mk) << 2)];

        fwht64(v);                   // FWHT-1b: e-bits {2..7}  (FWHT #1 done)

        // ---- multiply by g (pre-permuted, L1-resident) ----
        if (gq) {
#pragma unroll
            for (int m = 0; m < 16; ++m) {
                const float4 gv = *reinterpret_cast<const float4*>(gq + l * 64 + 4 * m);
                v[4 * m + 0] *= gv.x;
                v[4 * m + 1] *= gv.y;
                v[4 * m + 2] *= gv.z;
                v[4 * m + 3] *= gv.w;
            }
        } else {  // fallback if d_ws too small
#pragma unroll
            for (int k = 0; k < 64; ++k) {
                const int e = (l & 3) | (k << 2) | ((l >> 2) << 8);
                const float r  = g_rho[e];
                const float sp = (r > 20.f) ? r : log1pf(expf(r));
                v[k] *= g_mu[e] + sp * eps[e];
            }
        }

        fwht64(v);                   // FWHT-2a: e-bits {2..7}

        // ---- transpose 2: write layout B (b32), read layout A (b128) ----
        asm volatile("s_waitcnt lgkmcnt(0)" ::: "memory");   // T1 b32 reads drained (WAR)
#pragma unroll
        for (int k = 0; k < 64; ++k)
            lds[xb + ((k ^ mk) << 2)] = v[k];
        asm volatile("s_waitcnt lgkmcnt(0)" ::: "memory");   // writes visible
#pragma unroll
        for (int q = 0; q < 16; ++q) {
            const int addr = ((l ^ (q & 7)) << 2) + (q << 8);
            const float4 t = *reinterpret_cast<const float4*>(&lds[addr]);
            v[4 * q + 0] = t.x;
            v[4 * q + 1] = t.y;
            v[4 * q + 2] = t.z;
            v[4 * q + 3] = t.w;
        }
        asm volatile("s_waitcnt lgkmcnt(0)" ::: "memory");   // reads drained before next row (WAR)

        fwht64(v);                   // FWHT-2b: e-bits {0,1,8,9,10,11}

        // ---- multiply by s1, store (coalesced dwordx4) ----
        float* outr = out + row * (long long)D;
#pragma unroll
        for (int q = 0; q < 16; ++q) {
            const int base = (l << 2) + (q << 8);
            const float4 sv = *reinterpret_cast<const float4*>(s1 + base);
            float4 o;
            o.x = v[4 * q + 0] * sv.x;
            o.y = v[4 * q + 1] * sv.y;
            o.z = v[4 * q + 2] * sv.z;
            o.w = v[4 * q + 3] * sv.w;
            *reinterpret_cast<float4*>(outr + base) = o;
        }
    }
}

extern "C" void kernel_launch(void* const* d_in, const int* in_sizes, int n_in,
                              void* d_out, int out_size, void* d_ws, size_t ws_size,
                              hipStream_t stream) {
    const float* x     = (const float*)d_in[0];
    const float* s1    = (const float*)d_in[1];
    const float* s2    = (const float*)d_in[2];
    const float* g_mu  = (const float*)d_in[3];
    const float* g_rho = (const float*)d_in[4];
    const float* eps   = (const float*)d_in[5];
    float* out = (float*)d_out;
    const int rows = in_sizes[0] / D;

    float* gq = nullptr;
    if (ws_size >= (size_t)D * sizeof(float)) {
        gq = (float*)d_ws;
        whvi_prep<<<D / 64, 64, 0, stream>>>(g_mu, g_rho, eps, gq);
    }
    whvi_main<<<NBLK, WPB * 64, 0, stream>>>(x, s1, s2, gq, g_mu, g_rho, eps, out, rows);
}

// Round 9
// 291.185 us; speedup vs baseline: 1.1750x; 1.1750x over previous
//
#include <hip/hip_runtime.h>
#include <math.h>

#define D 4096
#define WPB 4      // waves per workgroup (256 threads); private 16 KiB LDS slice each
#define NBLK 512   // persistent: 2 WGs per CU (2 x 64 KiB LDS = 128 <= 160 KiB)

// In-register FWHT over the 6 bits of the register index (64 values/thread).
__device__ __forceinline__ void fwht64(float* v) {
#pragma unroll
    for (int h = 1; h < 64; h <<= 1) {
#pragma unroll
        for (int i = 0; i < 64; i += 2 * h) {
#pragma unroll
            for (int j = i; j < i + h; ++j) {
                const float a = v[j];
                const float b = v[j + h];
                v[j]     = a + b;
                v[j + h] = a - b;
            }
        }
    }
}

// Precompute g = g_mu + softplus(g_rho)*eps, pre-permuted into layout-B order:
// gq[l*64 + k] = g[e(k,l)], e = (l&3) | (k<<2) | ((l>>2)<<8)
__global__ void whvi_prep(const float* __restrict__ g_mu,
                          const float* __restrict__ g_rho,
                          const float* __restrict__ eps,
                          float* __restrict__ gq) {
    const int i = blockIdx.x * 64 + threadIdx.x;   // i = l*64 + k
    const int l = i >> 6, k = i & 63;
    const int e = (l & 3) | (k << 2) | ((l >> 2) << 8);
    const float r  = g_rho[e];
    const float sp = (r > 20.f) ? r : log1pf(expf(r));   // stable softplus
    gq[i] = g_mu[e] + sp * eps[e];
}

// DMA one full row (16 KB) into the wave's LDS slice, linear layout, ZERO VGPR
// temps. Per inst: 64 lanes x 16 B = 1 KB; LDS dest = uniform base + lane*16
// (matches linear layout exactly). Counted by vmcnt.
__device__ __forceinline__ void dma_row(const float* __restrict__ xr,
                                        float* lds, int l) {
#pragma unroll
    for (int q = 0; q < 16; ++q) {
        __builtin_amdgcn_global_load_lds(
            (const __attribute__((address_space(1))) void*)(xr + (l << 2) + (q << 8)),
            (__attribute__((address_space(3))) void*)(lds + (q << 8)),
            16, 0, 0);
    }
}

// PERSISTENT kernel; x staged via global_load_lds (no VGPR round-trip).
//
// LEDGER (r0-r8):
//  - HW residency: vgpr<=128 -> ~7-8 waves/CU achieved (r8); vgpr>=152 -> ~3.3
//    (r0/r4/r7, ALL launch shapes). So vgpr<=128 is mandatory for TLP.
//  - (256,2) -> budget 128 exactly (r8). BUT x staged through VGPRs (16 float4
//    hoisted temps = 64 regs on top of v[64]) spills at this budget
//    (r5 explicit xn[16]; r8 implicit scheduler hoist; both +250-650 MB HBM).
//    THIS round removes x from the register path entirely (DMA to LDS) and
//    pins constant-multiply load batches to 4 float4s via asm memory fences.
//  - Spill canary: WRITE_SIZE must be exactly 131072 KB, FETCH ~66 MB.
//
// Slice time-sharing: x occupies the 16 KiB slice from DMA-complete to the
// x->v read; T1/T2 transposes reuse the same slice afterwards (per-wave DS ops
// are ordered; compiler won't reorder may-aliasing LDS write before read).
// Next row's DMA is issued only after the T2-read drain fence (WAR-safe), and
// its ~900-1500 cyc latency hides under fwht2b + s1-mult + store (~1400 cyc).
//
// Layout A: lane l, reg r holds element e = (r&3) | (l<<2) | ((r>>2)<<8)
// Layout B: lane l, reg k holds element e = (l&3) | (k<<2) | ((l>>2)<<8)
// regFWHT(A) -> transpose -> regFWHT(B) covers all 12 bits. LDS xor-swizzle
// sigma(e)=e^((e>>6)&0x1C): b128 writes minimal-phase, b32 reads 2-way (free).
__global__ void __launch_bounds__(WPB * 64, 2) whvi_main(
    const float* __restrict__ x,  const float* __restrict__ s1,
    const float* __restrict__ s2, const float* __restrict__ gq,
    const float* __restrict__ g_mu, const float* __restrict__ g_rho,
    const float* __restrict__ eps, float* __restrict__ out, int rows) {
    __shared__ alignas(16) float lds_all[WPB * D];   // 64 KiB
    const int tid = threadIdx.x;
    const int w   = tid >> 6;                        // wave id in WG
    const int l   = tid & 63;                        // lane id
    float* lds = lds_all + (w << 12);                // private 16 KiB slice
    const int gw = blockIdx.x * WPB + w;             // global wave id
    const int nw = NBLK * WPB;                       // total waves (2048)
    const int xb = (l & 3) | ((l >> 2) << 8);        // layout-B read base
    const int mk = (l >> 2) & 7;                     // swizzle mask

    if (gw >= rows) return;                          // no barriers -> safe exit

    dma_row(x + (long long)gw * D, lds, l);          // prologue: first row's x

#pragma clang loop unroll(disable)
    for (long long row = gw; row < rows; row += nw) {
        const long long next = row + nw;
        float v[64];

        // ---- x is in LDS (DMA tracked by vmcnt; also drains prev stores) ----
        asm volatile("s_waitcnt vmcnt(0)" ::: "memory");

        // ---- v = x * s2; batches of 4 float4 cap the load-hoist depth ----
#pragma unroll
        for (int qb = 0; qb < 4; ++qb) {
#pragma unroll
            for (int qq = 0; qq < 4; ++qq) {
                const int q = qb * 4 + qq;
                const float4 xv = *reinterpret_cast<const float4*>(&lds[(q << 8) + (l << 2)]);
                const float4 sv = *reinterpret_cast<const float4*>(s2 + (l << 2) + (q << 8));
                v[4 * q + 0] = xv.x * sv.x;
                v[4 * q + 1] = xv.y * sv.y;
                v[4 * q + 2] = xv.z * sv.z;
                v[4 * q + 3] = xv.w * sv.w;
            }
            asm volatile("" ::: "memory");           // pin: max 4 float4 temps live
        }

        fwht64(v);                   // FWHT-1a: e-bits {0,1,8,9,10,11}

        // ---- transpose 1: write layout A (b128, swizzled), read layout B (b32) ----
        // (per-wave DS ordering: these writes cannot pass the x reads above)
#pragma unroll
        for (int q = 0; q < 16; ++q) {
            const int addr = ((l ^ (q & 7)) << 2) + (q << 8);
            *reinterpret_cast<float4*>(&lds[addr]) =
                make_float4(v[4 * q], v[4 * q + 1], v[4 * q + 2], v[4 * q + 3]);
        }
        asm volatile("s_waitcnt lgkmcnt(0)" ::: "memory");   // writes visible (wave-local)
#pragma unroll
        for (int k = 0; k < 64; ++k)
            v[k] = lds[xb + ((k ^ mk) << 2)];

        fwht64(v);                   // FWHT-1b: e-bits {2..7}  (FWHT #1 done)

        // ---- multiply by g (pre-permuted, L1-resident), batched ----
        if (gq) {
#pragma unroll
            for (int mb = 0; mb < 4; ++mb) {
#pragma unroll
                for (int mm = 0; mm < 4; ++mm) {
                    const int m = mb * 4 + mm;
                    const float4 gv = *reinterpret_cast<const float4*>(gq + l * 64 + 4 * m);
                    v[4 * m + 0] *= gv.x;
                    v[4 * m + 1] *= gv.y;
                    v[4 * m + 2] *= gv.z;
                    v[4 * m + 3] *= gv.w;
                }
                asm volatile("" ::: "memory");
            }
        } else {  // fallback if d_ws too small
#pragma unroll
            for (int k = 0; k < 64; ++k) {
                const int e = (l & 3) | (k << 2) | ((l >> 2) << 8);
                const float r  = g_rho[e];
                const float sp = (r > 20.f) ? r : log1pf(expf(r));
                v[k] *= g_mu[e] + sp * eps[e];
            }
        }

        fwht64(v);                   // FWHT-2a: e-bits {2..7}

        // ---- transpose 2: write layout B (b32), read layout A (b128) ----
        asm volatile("s_waitcnt lgkmcnt(0)" ::: "memory");   // T1 reads drained (WAR)
#pragma unroll
        for (int k = 0; k < 64; ++k)
            lds[xb + ((k ^ mk) << 2)] = v[k];
        asm volatile("s_waitcnt lgkmcnt(0)" ::: "memory");   // writes visible
#pragma unroll
        for (int q = 0; q < 16; ++q) {
            const int addr = ((l ^ (q & 7)) << 2) + (q << 8);
            const float4 t = *reinterpret_cast<const float4*>(&lds[addr]);
            v[4 * q + 0] = t.x;
            v[4 * q + 1] = t.y;
            v[4 * q + 2] = t.z;
            v[4 * q + 3] = t.w;
        }
        asm volatile("s_waitcnt lgkmcnt(0)" ::: "memory");   // T2 reads drained (WAR vs DMA)

        // ---- prefetch next row's x into the (now free) slice; hides under tail ----
        if (next < rows)
            dma_row(x + next * (long long)D, lds, l);

        fwht64(v);                   // FWHT-2b: e-bits {0,1,8,9,10,11}

        // ---- multiply by s1, store (coalesced dwordx4), batched ----
        float* outr = out + row * (long long)D;
#pragma unroll
        for (int qb = 0; qb < 4; ++qb) {
#pragma unroll
            for (int qq = 0; qq < 4; ++qq) {
                const int q = qb * 4 + qq;
                const int base = (l << 2) + (q << 8);
                const float4 sv = *reinterpret_cast<const float4*>(s1 + base);
                float4 o;
                o.x = v[4 * q + 0] * sv.x;
                o.y = v[4 * q + 1] * sv.y;
                o.z = v[4 * q + 2] * sv.z;
                o.w = v[4 * q + 3] * sv.w;
                *reinterpret_cast<float4*>(outr + base) = o;
            }
            asm volatile("" ::: "memory");
        }
    }
}

extern "C" void kernel_launch(void* const* d_in, const int* in_sizes, int n_in,
                              void* d_out, int out_size, void* d_ws, size_t ws_size,
                              hipStream_t stream) {
    const float* x     = (const float*)d_in[0];
    const float* s1    = (const float*)d_in[1];
    const float* s2    = (const float*)d_in[2];
    const float* g_mu  = (const float*)d_in[3];
    const float* g_rho = (const float*)d_in[4];
    const float* eps   = (const float*)d_in[5];
    float* out = (float*)d_out;
    const int rows = in_sizes[0] / D;

    float* gq = nullptr;
    if (ws_size >= (size_t)D * sizeof(float)) {
        gq = (float*)d_ws;
        whvi_prep<<<D / 64, 64, 0, stream>>>(g_mu, g_rho, eps, gq);
    }
    whvi_main<<<NBLK, WPB * 64, 0, stream>>>(x, s1, s2, gq, g_mu, g_rho, eps, out, rows);
}